// Round 12
// baseline (1012.837 us; speedup 1.0000x reference)
//
#include <hip/hip_runtime.h>
#include <hip/hip_cooperative_groups.h>
#include <math.h>

namespace cg = cooperative_groups;

#define NI 2048
#define NJ 32
#define ND 128
#define NV 32
#define NB 64
#define NCH 64  // i-chunks for partials: 64 chunks x 32 i each

typedef _Float16 f16x8 __attribute__((ext_vector_type(8)));
typedef float f32x4 __attribute__((ext_vector_type(4)));

__device__ __forceinline__ unsigned short f2h(float f) {
  _Float16 h = (_Float16)f;
  return __builtin_bit_cast(unsigned short, h);
}
__device__ __forceinline__ float h2f(unsigned short u) {
  return (float)__builtin_bit_cast(_Float16, u);
}

// ---------------------------------------------------------------------------
// K1: u_hat (fp16) = sum_d x[b,i,d] * W[i,j,d,v], stored uhat[J][I][B][V].
// R9 version verbatim (best, 468us).
// ---------------------------------------------------------------------------
#define LOADKS(dst, wp, ks)                                                    \
  {                                                                            \
    _Pragma("unroll") for (int mt = 0; mt < 2; ++mt) {                         \
      const float* ap =                                                        \
          (wp) + (size_t)((ks) * 32 + lg * 8) * NV + mt * 16 + li;             \
      _Pragma("unroll") for (int e = 0; e < 8; ++e)                            \
          dst[mt * 8 + e] = ap[(size_t)e * NV];                                \
    }                                                                          \
  }

__global__ __launch_bounds__(256, 3) void k_uhat(
    const float* __restrict__ x, const float* __restrict__ W,
    unsigned short* __restrict__ uhat) {
  const int i = blockIdx.x;
  const int tid = threadIdx.x;
  const int wave = tid >> 6;
  const int lane = tid & 63;
  __shared__ unsigned short xs[64][136];  // fp16 x_i tile, padded stride

  {
    const int b = tid >> 2;
    const int d0 = (tid & 3) * 32;
    const float* xp = x + ((size_t)b * NI + i) * ND + d0;
#pragma unroll
    for (int c2 = 0; c2 < 8; ++c2) {
      f32x4 v = *(const f32x4*)(xp + 4 * c2);
      ushort4 h;
      h.x = f2h(v.x); h.y = f2h(v.y); h.z = f2h(v.z); h.w = f2h(v.w);
      *(ushort4*)&xs[b][d0 + 4 * c2] = h;
    }
  }
  __syncthreads();

  const int li = lane & 15;
  const int lg = lane >> 4;

  // B fragments (x side): B[k=d][n=b]; lane holds n = li, k = 8*lg + e.
  f16x8 xfrag[4][4];
#pragma unroll
  for (int nt = 0; nt < 4; ++nt)
#pragma unroll
    for (int ks = 0; ks < 4; ++ks)
      xfrag[nt][ks] = *(const f16x8*)&xs[nt * 16 + li][ks * 32 + lg * 8];

  const float* wp0 = W + ((size_t)i * NJ + wave * 8) * (ND * NV);
  float raw[2][16];
  LOADKS(raw[0], wp0, 0)

#pragma unroll 1
  for (int jj = 0; jj < 8; ++jj) {
    const int j = wave * 8 + jj;
    const float* wp = wp0 + (size_t)jj * (ND * NV);
    f32x4 acc[2][4];
#pragma unroll
    for (int mt = 0; mt < 2; ++mt)
#pragma unroll
      for (int nt = 0; nt < 4; ++nt)
        acc[mt][nt] = (f32x4){0.f, 0.f, 0.f, 0.f};

#pragma unroll
    for (int ks = 0; ks < 4; ++ks) {
      const int cur = ks & 1;
      const int nxt = cur ^ 1;
      if (ks < 3) {
        LOADKS(raw[nxt], wp, ks + 1)
      } else {
        const int jn = (jj + 1) & 7;
        const float* wpn = wp0 + (size_t)jn * (ND * NV);
        LOADKS(raw[nxt], wpn, 0)
      }
      f16x8 wfrag[2];
#pragma unroll
      for (int mt = 0; mt < 2; ++mt) {
        f16x8 af;
#pragma unroll
        for (int e = 0; e < 8; ++e) af[e] = (_Float16)raw[cur][mt * 8 + e];
        wfrag[mt] = af;
      }
#pragma unroll
      for (int mt = 0; mt < 2; ++mt)
#pragma unroll
        for (int nt = 0; nt < 4; ++nt)
          acc[mt][nt] = __builtin_amdgcn_mfma_f32_16x16x32_f16(
              wfrag[mt], xfrag[nt][ks], acc[mt][nt], 0, 0, 0);
    }

    unsigned short* up = uhat + ((size_t)j * NI + i) * (NB * NV);
#pragma unroll
    for (int mt = 0; mt < 2; ++mt)
#pragma unroll
      for (int nt = 0; nt < 4; ++nt) {
        const int b = nt * 16 + li;
        const int v0 = mt * 16 + lg * 4;
        ushort4 h4;
        h4.x = f2h(acc[mt][nt][0]);
        h4.y = f2h(acc[mt][nt][1]);
        h4.z = f2h(acc[mt][nt][2]);
        h4.w = f2h(acc[mt][nt][3]);
        *(ushort4*)(up + (size_t)b * NV + v0) = h4;
      }
  }
}

// ---------------------------------------------------------------------------
// phase bodies (shared by coop kernel and fallback kernels)
// ---------------------------------------------------------------------------
__device__ __forceinline__ void pass0_body(
    int task, const unsigned short* __restrict__ uhat,
    float* __restrict__ spart) {
  const int j = task & 31;
  const int ch = task >> 5;
  const int tid = threadIdx.x;
  const int f0 = tid * 8;
  float acc[8] = {0, 0, 0, 0, 0, 0, 0, 0};
  const int i0 = ch * 32;
  const unsigned short* ubase = uhat + ((size_t)j * NI + i0) * (NB * NV) + f0;
#pragma unroll 4
  for (int ii = 0; ii < 32; ++ii) {
    const uint4 q = *(const uint4*)(ubase + (size_t)ii * (NB * NV));
    acc[0] += h2f((unsigned short)(q.x & 0xffff));
    acc[1] += h2f((unsigned short)(q.x >> 16));
    acc[2] += h2f((unsigned short)(q.y & 0xffff));
    acc[3] += h2f((unsigned short)(q.y >> 16));
    acc[4] += h2f((unsigned short)(q.z & 0xffff));
    acc[5] += h2f((unsigned short)(q.z >> 16));
    acc[6] += h2f((unsigned short)(q.w & 0xffff));
    acc[7] += h2f((unsigned short)(q.w >> 16));
  }
  const int b = f0 >> 5;
  const int v0 = f0 & 31;
  float* sp = spart + (size_t)ch * (NB * NJ * NV) + (size_t)b * (NJ * NV) + j * NV + v0;
  *(f32x4*)sp = (f32x4){acc[0], acc[1], acc[2], acc[3]};
  *(f32x4*)(sp + 4) = (f32x4){acc[4], acc[5], acc[6], acc[7]};
}

__device__ __forceinline__ void route_body(
    int task, const unsigned short* __restrict__ uhat,
    const float* __restrict__ vprev, const float* __restrict__ bin,
    float* __restrict__ bout, float* __restrict__ spart,
    float* __restrict__ Zpart, float (&red)[2][4]) {
  const int j = task & 31;
  const int ch = task >> 5;
  const int tid = threadIdx.x;
  const int wave = tid >> 6;
  const int lane = tid & 63;
  const int f0 = tid * 8;
  const int b = f0 >> 5;
  const int v0 = f0 & 31;

  const float* vp = vprev + (size_t)b * (NJ * NV) + j * NV + v0;
  const f32x4 vva = *(const f32x4*)vp;
  const f32x4 vvb = *(const f32x4*)(vp + 4);

  float acc[8] = {0, 0, 0, 0, 0, 0, 0, 0};
  float zacc = 0.0f;
  const int i0 = ch * 32;
  const float* binj = bin ? (bin + (size_t)j * NI) : nullptr;
  float* boutj = bout + (size_t)j * NI;
  const unsigned short* ubase = uhat + ((size_t)j * NI + i0) * (NB * NV) + f0;

#pragma unroll 2
  for (int ii = 0; ii < 32; ++ii) {
    const int i = i0 + ii;
    const float bprev = binj ? binj[i] : 0.0f;
    const uint4 q = *(const uint4*)(ubase + (size_t)ii * (NB * NV));
    float h[8];
    h[0] = h2f((unsigned short)(q.x & 0xffff));
    h[1] = h2f((unsigned short)(q.x >> 16));
    h[2] = h2f((unsigned short)(q.y & 0xffff));
    h[3] = h2f((unsigned short)(q.y >> 16));
    h[4] = h2f((unsigned short)(q.z & 0xffff));
    h[5] = h2f((unsigned short)(q.z >> 16));
    h[6] = h2f((unsigned short)(q.w & 0xffff));
    h[7] = h2f((unsigned short)(q.w >> 16));
    float dp = h[0] * vva.x + h[1] * vva.y + h[2] * vva.z + h[3] * vva.w +
               h[4] * vvb.x + h[5] * vvb.y + h[6] * vvb.z + h[7] * vvb.w;
#pragma unroll
    for (int off = 32; off > 0; off >>= 1) dp += __shfl_xor(dp, off);
    const int par = ii & 1;
    if (lane == 0) red[par][wave] = dp;
    __syncthreads();
    const float agree = red[par][0] + red[par][1] + red[par][2] + red[par][3];
    const float bnew = bprev + agree * (1.0f / 64.0f);
    const float w = __expf(bnew);
    if (tid == 0) boutj[i] = bnew;
#pragma unroll
    for (int e = 0; e < 8; ++e) acc[e] = fmaf(w, h[e], acc[e]);
    zacc += w;
  }
  if (tid == 0) Zpart[ch * NJ + j] = zacc;
  float* sp = spart + (size_t)ch * (NB * NJ * NV) + (size_t)b * (NJ * NV) + j * NV + v0;
  *(f32x4*)sp = (f32x4){acc[0], acc[1], acc[2], acc[3]};
  *(f32x4*)(sp + 4) = (f32x4){acc[4], acc[5], acc[6], acc[7]};
}

// squash for 256-thread blocks: thread handles slots tid+256k (k=0..3).
__device__ __forceinline__ void squash_body(
    int b, const float* __restrict__ spart, const float* __restrict__ Zpart,
    float scale0, float* __restrict__ vout, float (&sq)[NJ][NV + 1],
    float (&zinv)[NJ], float (&msq)[NV]) {
  const int tid = threadIdx.x;
  if (Zpart != nullptr) {
    if (tid < NJ) {
      float z = 0.0f;
#pragma unroll 8
      for (int ch = 0; ch < NCH; ++ch) z += Zpart[ch * NJ + tid];
      zinv[tid] = 1.0f / z;
    }
    __syncthreads();
  }
  float sv[4];
#pragma unroll
  for (int k = 0; k < 4; ++k) {
    const int slot = tid + 256 * k;
    const int j = slot >> 5;
    float s = 0.0f;
#pragma unroll 8
    for (int ch = 0; ch < NCH; ++ch)
      s += spart[(size_t)ch * (NB * NJ * NV) + (size_t)b * (NJ * NV) + slot];
    s *= (Zpart != nullptr) ? zinv[j] : scale0;
    sv[k] = s;
    sq[j][slot & 31] = s * s;
  }
  __syncthreads();
  if (tid < NV) {
    float m = 0.0f;
#pragma unroll
    for (int j = 0; j < NJ; ++j) m += sq[j][tid];
    msq[tid] = m;
  }
  __syncthreads();
#pragma unroll
  for (int k = 0; k < 4; ++k) {
    const int slot = tid + 256 * k;
    const float m = msq[slot & 31];
    const float f = m / ((1.0f + m) * sqrtf(m + 1e-9f));
    vout[(size_t)b * (NJ * NV) + slot] = f * sv[k];
  }
  __syncthreads();  // LDS reuse guard
}

// ---------------------------------------------------------------------------
// Fused cooperative routing. Grid sized at runtime from the occupancy query
// (R11 failed because grid=1024 exceeded the legal coop grid).
// ---------------------------------------------------------------------------
__global__ __launch_bounds__(256, 4) void k_routing(
    const unsigned short* __restrict__ uhat, float* __restrict__ bbuf,
    float* __restrict__ spart, float* __restrict__ Zpart,
    float* __restrict__ vt, float* __restrict__ out) {
  cg::grid_group grid = cg::this_grid();
  __shared__ float red[2][4];
  __shared__ float sq[NJ][NV + 1];
  __shared__ float zinv[NJ];
  __shared__ float msq[NV];

  for (int t = blockIdx.x; t < NCH * NJ; t += gridDim.x)
    pass0_body(t, uhat, spart);
  grid.sync();
  for (int b = blockIdx.x; b < NB; b += gridDim.x)
    squash_body(b, spart, nullptr, 1.0f / NI, vt, sq, zinv, msq);
  grid.sync();
  for (int t = blockIdx.x; t < NCH * NJ; t += gridDim.x)
    route_body(t, uhat, vt, nullptr, bbuf, spart, Zpart, red);
  grid.sync();
  for (int b = blockIdx.x; b < NB; b += gridDim.x)
    squash_body(b, spart, Zpart, 0.0f, vt, sq, zinv, msq);
  grid.sync();
  for (int t = blockIdx.x; t < NCH * NJ; t += gridDim.x)
    route_body(t, uhat, vt, bbuf, bbuf, spart, Zpart, red);
  grid.sync();
  for (int b = blockIdx.x; b < NB; b += gridDim.x)
    squash_body(b, spart, Zpart, 0.0f, out, sq, zinv, msq);
}

// ---------------------------------------------------------------------------
// Fallback standalone kernels (R9-proven, used if the coop launch fails)
// ---------------------------------------------------------------------------
__global__ __launch_bounds__(256) void k_pass0(
    const unsigned short* __restrict__ uhat, float* __restrict__ spart) {
  pass0_body(blockIdx.x, uhat, spart);
}

__global__ __launch_bounds__(256) void k_route(
    const unsigned short* __restrict__ uhat, const float* __restrict__ vprev,
    const float* __restrict__ bin, float* __restrict__ bout,
    float* __restrict__ spart, float* __restrict__ Zpart) {
  __shared__ float red[2][4];
  route_body(blockIdx.x, uhat, vprev, bin, bout, spart, Zpart, red);
}

__global__ __launch_bounds__(256) void k_squash(
    const float* __restrict__ spart, const float* __restrict__ Zpart,
    const float scale0, float* __restrict__ vout) {
  __shared__ float sq[NJ][NV + 1];
  __shared__ float zinv[NJ];
  __shared__ float msq[NV];
  squash_body(blockIdx.x, spart, Zpart, scale0, vout, sq, zinv, msq);
}

// ---------------------------------------------------------------------------
extern "C" void kernel_launch(void* const* d_in, const int* in_sizes, int n_in,
                              void* d_out, int out_size, void* d_ws, size_t ws_size,
                              hipStream_t stream) {
  (void)in_sizes; (void)n_in; (void)out_size; (void)ws_size;
  const float* x = (const float*)d_in[0];
  const float* W = (const float*)d_in[1];
  float* outp = (float*)d_out;

  char* ws = (char*)d_ws;
  const size_t UHAT_BYTES = (size_t)NI * NJ * NB * NV * 2;  // 268,435,456
  unsigned short* uhat = (unsigned short*)ws;                // [NJ][NI][NB][NV]
  float* bbuf = (float*)(ws + UHAT_BYTES);            // [NJ][NI]
  float* spart = bbuf + (size_t)NI * NJ;              // [NCH][NB][NJ][NV]
  float* vt = spart + (size_t)NCH * NB * NJ * NV;     // [NB][NJ][NV]
  float* Zpart = vt + (size_t)NB * NJ * NV;           // [NCH][NJ]

  k_uhat<<<dim3(NI), dim3(256), 0, stream>>>(x, W, uhat);

  // size coop grid from real occupancy (host-side query; capture-safe)
  int maxBlk = 0;
  hipError_t qe = hipOccupancyMaxActiveBlocksPerMultiprocessor(
      &maxBlk, (const void*)k_routing, 256, 0);
  hipError_t le = hipErrorUnknown;
  if (qe == hipSuccess && maxBlk >= 1) {
    int grid = maxBlk * 256;             // 256 CUs
    if (grid > NCH * NJ) grid = NCH * NJ;
    void* args[] = {(void*)&uhat, (void*)&bbuf, (void*)&spart,
                    (void*)&Zpart, (void*)&vt, (void*)&outp};
    le = hipLaunchCooperativeKernel((const void*)k_routing, dim3(grid),
                                    dim3(256), args, 0, stream);
  }
  if (le != hipSuccess) {
    // fallback: R9 7-kernel chain (identical math)
    k_pass0<<<dim3(NCH * NJ), dim3(256), 0, stream>>>(uhat, spart);
    k_squash<<<dim3(NB), dim3(256), 0, stream>>>(spart, nullptr, 1.0f / NI, vt);
    k_route<<<dim3(NCH * NJ), dim3(256), 0, stream>>>(uhat, vt, nullptr, bbuf,
                                                      spart, Zpart);
    k_squash<<<dim3(NB), dim3(256), 0, stream>>>(spart, Zpart, 0.0f, vt);
    k_route<<<dim3(NCH * NJ), dim3(256), 0, stream>>>(uhat, vt, bbuf, bbuf,
                                                      spart, Zpart);
    k_squash<<<dim3(NB), dim3(256), 0, stream>>>(spart, Zpart, 0.0f, outp);
  }
}

// Round 14
// 472.314 us; speedup vs baseline: 2.1444x; 2.1444x over previous
//
#include <hip/hip_runtime.h>
#include <math.h>

#define NI 2048
#define NJ 32
#define ND 128
#define NV 32
#define NB 64
#define NCH 64  // i-chunks for partials: 64 chunks x 32 i each

typedef _Float16 f16x8 __attribute__((ext_vector_type(8)));
typedef float f32x4 __attribute__((ext_vector_type(4)));

__device__ __forceinline__ unsigned short f2h(float f) {
  _Float16 h = (_Float16)f;
  return __builtin_bit_cast(unsigned short, h);
}
__device__ __forceinline__ float h2f(unsigned short u) {
  return (float)__builtin_bit_cast(_Float16, u);
}

// ---------------------------------------------------------------------------
// K1: u_hat (fp16) = sum_d x[b,i,d] * W[i,j,d,v], stored uhat[J][I][B][V].
// R9 version verbatim (best, 468us).
// ---------------------------------------------------------------------------
#define LOADKS(dst, wp, ks)                                                    \
  {                                                                            \
    _Pragma("unroll") for (int mt = 0; mt < 2; ++mt) {                         \
      const float* ap =                                                        \
          (wp) + (size_t)((ks) * 32 + lg * 8) * NV + mt * 16 + li;             \
      _Pragma("unroll") for (int e = 0; e < 8; ++e)                            \
          dst[mt * 8 + e] = ap[(size_t)e * NV];                                \
    }                                                                          \
  }

__global__ __launch_bounds__(256, 3) void k_uhat(
    const float* __restrict__ x, const float* __restrict__ W,
    unsigned short* __restrict__ uhat) {
  const int i = blockIdx.x;
  const int tid = threadIdx.x;
  const int wave = tid >> 6;
  const int lane = tid & 63;
  __shared__ unsigned short xs[64][136];  // fp16 x_i tile, padded stride

  {
    const int b = tid >> 2;
    const int d0 = (tid & 3) * 32;
    const float* xp = x + ((size_t)b * NI + i) * ND + d0;
#pragma unroll
    for (int c2 = 0; c2 < 8; ++c2) {
      f32x4 v = *(const f32x4*)(xp + 4 * c2);
      ushort4 h;
      h.x = f2h(v.x); h.y = f2h(v.y); h.z = f2h(v.z); h.w = f2h(v.w);
      *(ushort4*)&xs[b][d0 + 4 * c2] = h;
    }
  }
  __syncthreads();

  const int li = lane & 15;
  const int lg = lane >> 4;

  // B fragments (x side): B[k=d][n=b]; lane holds n = li, k = 8*lg + e.
  f16x8 xfrag[4][4];
#pragma unroll
  for (int nt = 0; nt < 4; ++nt)
#pragma unroll
    for (int ks = 0; ks < 4; ++ks)
      xfrag[nt][ks] = *(const f16x8*)&xs[nt * 16 + li][ks * 32 + lg * 8];

  const float* wp0 = W + ((size_t)i * NJ + wave * 8) * (ND * NV);
  float raw[2][16];
  LOADKS(raw[0], wp0, 0)

#pragma unroll 1
  for (int jj = 0; jj < 8; ++jj) {
    const int j = wave * 8 + jj;
    const float* wp = wp0 + (size_t)jj * (ND * NV);
    f32x4 acc[2][4];
#pragma unroll
    for (int mt = 0; mt < 2; ++mt)
#pragma unroll
      for (int nt = 0; nt < 4; ++nt)
        acc[mt][nt] = (f32x4){0.f, 0.f, 0.f, 0.f};

#pragma unroll
    for (int ks = 0; ks < 4; ++ks) {
      const int cur = ks & 1;
      const int nxt = cur ^ 1;
      if (ks < 3) {
        LOADKS(raw[nxt], wp, ks + 1)
      } else {
        const int jn = (jj + 1) & 7;
        const float* wpn = wp0 + (size_t)jn * (ND * NV);
        LOADKS(raw[nxt], wpn, 0)
      }
      f16x8 wfrag[2];
#pragma unroll
      for (int mt = 0; mt < 2; ++mt) {
        f16x8 af;
#pragma unroll
        for (int e = 0; e < 8; ++e) af[e] = (_Float16)raw[cur][mt * 8 + e];
        wfrag[mt] = af;
      }
#pragma unroll
      for (int mt = 0; mt < 2; ++mt)
#pragma unroll
        for (int nt = 0; nt < 4; ++nt)
          acc[mt][nt] = __builtin_amdgcn_mfma_f32_16x16x32_f16(
              wfrag[mt], xfrag[nt][ks], acc[mt][nt], 0, 0, 0);
    }

    unsigned short* up = uhat + ((size_t)j * NI + i) * (NB * NV);
#pragma unroll
    for (int mt = 0; mt < 2; ++mt)
#pragma unroll
      for (int nt = 0; nt < 4; ++nt) {
        const int b = nt * 16 + li;
        const int v0 = mt * 16 + lg * 4;
        ushort4 h4;
        h4.x = f2h(acc[mt][nt][0]);
        h4.y = f2h(acc[mt][nt][1]);
        h4.z = f2h(acc[mt][nt][2]);
        h4.w = f2h(acc[mt][nt][3]);
        *(ushort4*)(up + (size_t)b * NV + v0) = h4;
      }
  }
}

// ---------------------------------------------------------------------------
// pass0: spart[ch][b][j][v] = sum_{i in chunk} u_hat[j][i][b][v]
// Block (ch,j) reads a 128-KB contiguous span. grid = 64ch x 32j. (R9)
// ---------------------------------------------------------------------------
__global__ __launch_bounds__(256) void k_pass0(
    const unsigned short* __restrict__ uhat, float* __restrict__ spart) {
  const int j = blockIdx.x & 31;
  const int ch = blockIdx.x >> 5;
  const int tid = threadIdx.x;
  const int f0 = tid * 8;
  float acc[8] = {0, 0, 0, 0, 0, 0, 0, 0};
  const int i0 = ch * 32;
  const unsigned short* ubase = uhat + ((size_t)j * NI + i0) * (NB * NV) + f0;
#pragma unroll 4
  for (int ii = 0; ii < 32; ++ii) {
    const uint4 q = *(const uint4*)(ubase + (size_t)ii * (NB * NV));
    acc[0] += h2f((unsigned short)(q.x & 0xffff));
    acc[1] += h2f((unsigned short)(q.x >> 16));
    acc[2] += h2f((unsigned short)(q.y & 0xffff));
    acc[3] += h2f((unsigned short)(q.y >> 16));
    acc[4] += h2f((unsigned short)(q.z & 0xffff));
    acc[5] += h2f((unsigned short)(q.z >> 16));
    acc[6] += h2f((unsigned short)(q.w & 0xffff));
    acc[7] += h2f((unsigned short)(q.w >> 16));
  }
  const int b = f0 >> 5;
  const int v0 = f0 & 31;
  float* sp = spart + (size_t)ch * (NB * NJ * NV) + (size_t)b * (NJ * NV) + j * NV + v0;
  *(f32x4*)sp = (f32x4){acc[0], acc[1], acc[2], acc[3]};
  *(f32x4*)(sp + 4) = (f32x4){acc[4], acc[5], acc[6], acc[7]};
}

// ---------------------------------------------------------------------------
// fused routing pass (iterations 1,2), 4-i batched (SINGLE CHANGE vs R9):
//  phase A: 4 loads -> h[4][8] (32 VGPR) -> 4 thread-local dots -> dp_lds
//  phase B: wave w tree-reduces row w (256 partials) -> agree_lds [barrier x2]
//  phase C: w = exp(bprev + agree/64); acc += w*h (registers)
// 2 barriers per 4 i instead of 1 per i. Deterministic reduce tree.
// ---------------------------------------------------------------------------
__global__ __launch_bounds__(256) void k_route(
    const unsigned short* __restrict__ uhat, const float* __restrict__ vprev,
    const float* __restrict__ bin, float* __restrict__ bout,
    float* __restrict__ spart, float* __restrict__ Zpart) {
  const int j = blockIdx.x & 31;
  const int ch = blockIdx.x >> 5;
  const int tid = threadIdx.x;
  const int wave = tid >> 6;
  const int lane = tid & 63;
  const int f0 = tid * 8;
  const int b = f0 >> 5;
  const int v0 = f0 & 31;

  __shared__ float dp_lds[4][256];
  __shared__ float agree_lds[4];

  const float* vp = vprev + (size_t)b * (NJ * NV) + j * NV + v0;
  const f32x4 vva = *(const f32x4*)vp;
  const f32x4 vvb = *(const f32x4*)(vp + 4);

  float acc[8] = {0, 0, 0, 0, 0, 0, 0, 0};
  float zacc = 0.0f;
  const int i0 = ch * 32;
  const float* binj = bin ? (bin + (size_t)j * NI) : nullptr;
  float* boutj = bout + (size_t)j * NI;
  const unsigned short* ubase = uhat + ((size_t)j * NI + i0) * (NB * NV) + f0;

#pragma unroll 1
  for (int g = 0; g < 8; ++g) {
    const int ig = g * 4;
    float h[4][8];
    float dp[4];
#pragma unroll
    for (int r = 0; r < 4; ++r) {
      const uint4 q = *(const uint4*)(ubase + (size_t)(ig + r) * (NB * NV));
      h[r][0] = h2f((unsigned short)(q.x & 0xffff));
      h[r][1] = h2f((unsigned short)(q.x >> 16));
      h[r][2] = h2f((unsigned short)(q.y & 0xffff));
      h[r][3] = h2f((unsigned short)(q.y >> 16));
      h[r][4] = h2f((unsigned short)(q.z & 0xffff));
      h[r][5] = h2f((unsigned short)(q.z >> 16));
      h[r][6] = h2f((unsigned short)(q.w & 0xffff));
      h[r][7] = h2f((unsigned short)(q.w >> 16));
      dp[r] = h[r][0] * vva.x + h[r][1] * vva.y + h[r][2] * vva.z +
              h[r][3] * vva.w + h[r][4] * vvb.x + h[r][5] * vvb.y +
              h[r][6] * vvb.z + h[r][7] * vvb.w;
    }
#pragma unroll
    for (int r = 0; r < 4; ++r) dp_lds[r][tid] = dp[r];
    __syncthreads();
    {
      // wave `wave` reduces row `wave` (one row per wave)
      float s = dp_lds[wave][lane] + dp_lds[wave][lane + 64] +
                dp_lds[wave][lane + 128] + dp_lds[wave][lane + 192];
#pragma unroll
      for (int off = 32; off > 0; off >>= 1) s += __shfl_xor(s, off);
      if (lane == 0) agree_lds[wave] = s;
    }
    __syncthreads();
#pragma unroll
    for (int r = 0; r < 4; ++r) {
      const int i = i0 + ig + r;
      const float bprev = binj ? binj[i] : 0.0f;  // uniform -> scalar load
      const float bnew = bprev + agree_lds[r] * (1.0f / 64.0f);
      const float w = __expf(bnew);
      zacc += w;
#pragma unroll
      for (int e = 0; e < 8; ++e) acc[e] = fmaf(w, h[r][e], acc[e]);
    }
    if (tid < 4) {
      const int i = i0 + ig + tid;
      const float bprev = binj ? binj[i] : 0.0f;
      boutj[i] = bprev + agree_lds[tid] * (1.0f / 64.0f);
    }
  }
  if (tid == 0) Zpart[ch * NJ + j] = zacc;
  float* sp = spart + (size_t)ch * (NB * NJ * NV) + (size_t)b * (NJ * NV) + j * NV + v0;
  *(f32x4*)sp = (f32x4){acc[0], acc[1], acc[2], acc[3]};
  *(f32x4*)(sp + 4) = (f32x4){acc[4], acc[5], acc[6], acc[7]};
}

// ---------------------------------------------------------------------------
// squash: s[b][j][v] = scale_j * sum_ch spart ; msq over j per (b,v);
// vout = msq/(1+msq) * s / sqrt(msq + 1e-9).  scale_j = 1/Z_j or scale0. (R9)
// ---------------------------------------------------------------------------
__global__ __launch_bounds__(1024) void k_squash(
    const float* __restrict__ spart, const float* __restrict__ Zpart,
    const float scale0, float* __restrict__ vout) {
  const int b = blockIdx.x;
  const int tid = threadIdx.x;
  const int j = tid >> 5;
  const int v = tid & 31;
  __shared__ float zs[NJ];
  if (Zpart != nullptr) {
    if (tid < NJ) {
      float z = 0.0f;
#pragma unroll 8
      for (int ch = 0; ch < NCH; ++ch) z += Zpart[ch * NJ + tid];
      zs[tid] = 1.0f / z;
    }
    __syncthreads();
  }
  const float scale = (Zpart != nullptr) ? zs[j] : scale0;
  float s = 0.0f;
#pragma unroll 8
  for (int ch = 0; ch < NCH; ++ch)
    s += spart[(size_t)ch * (NB * NJ * NV) + (size_t)b * (NJ * NV) + tid];
  s *= scale;
  __shared__ float sq[NJ][NV + 1];
  sq[j][v] = s * s;
  __syncthreads();
#pragma unroll
  for (int off = 16; off > 0; off >>= 1) {
    if (j < off) sq[j][v] += sq[j + off][v];
    __syncthreads();
  }
  const float msq = sq[0][v];
  const float f = msq / ((1.0f + msq) * sqrtf(msq + 1e-9f));
  vout[(size_t)b * (NJ * NV) + tid] = f * s;
}

// ---------------------------------------------------------------------------
extern "C" void kernel_launch(void* const* d_in, const int* in_sizes, int n_in,
                              void* d_out, int out_size, void* d_ws, size_t ws_size,
                              hipStream_t stream) {
  (void)in_sizes; (void)n_in; (void)out_size; (void)ws_size;
  const float* x = (const float*)d_in[0];
  const float* W = (const float*)d_in[1];
  float* out = (float*)d_out;

  char* ws = (char*)d_ws;
  const size_t UHAT_BYTES = (size_t)NI * NJ * NB * NV * 2;  // 268,435,456
  unsigned short* uhat = (unsigned short*)ws;                // [NJ][NI][NB][NV]
  float* bbuf = (float*)(ws + UHAT_BYTES);            // [NJ][NI]
  float* spart = bbuf + (size_t)NI * NJ;              // [NCH][NB][NJ][NV]
  float* vt = spart + (size_t)NCH * NB * NJ * NV;     // [NB][NJ][NV]
  float* Zpart = vt + (size_t)NB * NJ * NV;           // [NCH][NJ]

  k_uhat<<<dim3(NI), dim3(256), 0, stream>>>(x, W, uhat);

  // it0: c uniform -> s0 partials, squash with scale 1/2048
  k_pass0<<<dim3(NCH * NJ), dim3(256), 0, stream>>>(uhat, spart);
  k_squash<<<dim3(NB), dim3(1024), 0, stream>>>(spart, nullptr, 1.0f / NI, vt);

  // it1: agree0 + unnormalized s1 in one pass (b starts at 0)
  k_route<<<dim3(NCH * NJ), dim3(256), 0, stream>>>(uhat, vt, nullptr, bbuf, spart, Zpart);
  k_squash<<<dim3(NB), dim3(1024), 0, stream>>>(spart, Zpart, 0.0f, vt);

  // it2: agree1 + unnormalized s2 in one pass
  k_route<<<dim3(NCH * NJ), dim3(256), 0, stream>>>(uhat, vt, bbuf, bbuf, spart, Zpart);
  k_squash<<<dim3(NB), dim3(1024), 0, stream>>>(spart, Zpart, 0.0f, out);
}

// Round 15
// 468.475 us; speedup vs baseline: 2.1620x; 1.0082x over previous
//
#include <hip/hip_runtime.h>
#include <math.h>

#define NI 2048
#define NJ 32
#define ND 128
#define NV 32
#define NB 64
#define NCH 64  // i-chunks for partials: 64 chunks x 32 i each

typedef _Float16 f16x8 __attribute__((ext_vector_type(8)));
typedef float f32x4 __attribute__((ext_vector_type(4)));

__device__ __forceinline__ unsigned short f2h(float f) {
  _Float16 h = (_Float16)f;
  return __builtin_bit_cast(unsigned short, h);
}
__device__ __forceinline__ float h2f(unsigned short u) {
  return (float)__builtin_bit_cast(_Float16, u);
}

// ---------------------------------------------------------------------------
// FINAL (R9, best measured 468us). Session ledger:
//   kept: MFMA operand swap (A=W m=v) + ushort4 epilogue (R7, +10us);
//         uhat layout [J][I][B][V] (R9, +8us); fused agree+s pass (R2, -141us);
//         NCH=64 grids + lb(256,3) (R5, -21us).
//   rejected: NT hints (-76), LDS-reread/occ4 (-17), global_load_lds (0),
//             coop grid-sync fusion (-544), fp8 uhat (precision fail),
//             batched route barriers (0).
// Traffic floor ~370us at 6.3TB/s achievable; this runs at 468us with every
// kernel at 75-85% of pure-copy BW while doing MFMA/exp/reduce work.
// ---------------------------------------------------------------------------
#define LOADKS(dst, wp, ks)                                                    \
  {                                                                            \
    _Pragma("unroll") for (int mt = 0; mt < 2; ++mt) {                         \
      const float* ap =                                                        \
          (wp) + (size_t)((ks) * 32 + lg * 8) * NV + mt * 16 + li;             \
      _Pragma("unroll") for (int e = 0; e < 8; ++e)                            \
          dst[mt * 8 + e] = ap[(size_t)e * NV];                                \
    }                                                                          \
  }

__global__ __launch_bounds__(256, 3) void k_uhat(
    const float* __restrict__ x, const float* __restrict__ W,
    unsigned short* __restrict__ uhat) {
  const int i = blockIdx.x;
  const int tid = threadIdx.x;
  const int wave = tid >> 6;
  const int lane = tid & 63;
  __shared__ unsigned short xs[64][136];  // fp16 x_i tile, padded stride

  {
    const int b = tid >> 2;
    const int d0 = (tid & 3) * 32;
    const float* xp = x + ((size_t)b * NI + i) * ND + d0;
#pragma unroll
    for (int c2 = 0; c2 < 8; ++c2) {
      f32x4 v = *(const f32x4*)(xp + 4 * c2);
      ushort4 h;
      h.x = f2h(v.x); h.y = f2h(v.y); h.z = f2h(v.z); h.w = f2h(v.w);
      *(ushort4*)&xs[b][d0 + 4 * c2] = h;
    }
  }
  __syncthreads();

  const int li = lane & 15;
  const int lg = lane >> 4;

  // B fragments (x side): B[k=d][n=b]; lane holds n = li, k = 8*lg + e.
  f16x8 xfrag[4][4];
#pragma unroll
  for (int nt = 0; nt < 4; ++nt)
#pragma unroll
    for (int ks = 0; ks < 4; ++ks)
      xfrag[nt][ks] = *(const f16x8*)&xs[nt * 16 + li][ks * 32 + lg * 8];

  const float* wp0 = W + ((size_t)i * NJ + wave * 8) * (ND * NV);
  float raw[2][16];
  LOADKS(raw[0], wp0, 0)

#pragma unroll 1
  for (int jj = 0; jj < 8; ++jj) {
    const int j = wave * 8 + jj;
    const float* wp = wp0 + (size_t)jj * (ND * NV);
    f32x4 acc[2][4];
#pragma unroll
    for (int mt = 0; mt < 2; ++mt)
#pragma unroll
      for (int nt = 0; nt < 4; ++nt)
        acc[mt][nt] = (f32x4){0.f, 0.f, 0.f, 0.f};

#pragma unroll
    for (int ks = 0; ks < 4; ++ks) {
      const int cur = ks & 1;
      const int nxt = cur ^ 1;
      if (ks < 3) {
        LOADKS(raw[nxt], wp, ks + 1)
      } else {
        const int jn = (jj + 1) & 7;
        const float* wpn = wp0 + (size_t)jn * (ND * NV);
        LOADKS(raw[nxt], wpn, 0)
      }
      f16x8 wfrag[2];
#pragma unroll
      for (int mt = 0; mt < 2; ++mt) {
        f16x8 af;
#pragma unroll
        for (int e = 0; e < 8; ++e) af[e] = (_Float16)raw[cur][mt * 8 + e];
        wfrag[mt] = af;
      }
#pragma unroll
      for (int mt = 0; mt < 2; ++mt)
#pragma unroll
        for (int nt = 0; nt < 4; ++nt)
          acc[mt][nt] = __builtin_amdgcn_mfma_f32_16x16x32_f16(
              wfrag[mt], xfrag[nt][ks], acc[mt][nt], 0, 0, 0);
    }

    // C layout: col(n=b_local) = lane&15, row(m=v_local) = 4*(lane>>4)+reg.
    unsigned short* up = uhat + ((size_t)j * NI + i) * (NB * NV);
#pragma unroll
    for (int mt = 0; mt < 2; ++mt)
#pragma unroll
      for (int nt = 0; nt < 4; ++nt) {
        const int b = nt * 16 + li;
        const int v0 = mt * 16 + lg * 4;
        ushort4 h4;
        h4.x = f2h(acc[mt][nt][0]);
        h4.y = f2h(acc[mt][nt][1]);
        h4.z = f2h(acc[mt][nt][2]);
        h4.w = f2h(acc[mt][nt][3]);
        *(ushort4*)(up + (size_t)b * NV + v0) = h4;
      }
  }
}

// ---------------------------------------------------------------------------
// pass0: spart[ch][b][j][v] = sum_{i in chunk} u_hat[j][i][b][v]
// Block (ch,j) reads a 128-KB contiguous span. grid = 64ch x 32j.
// ---------------------------------------------------------------------------
__global__ __launch_bounds__(256) void k_pass0(
    const unsigned short* __restrict__ uhat, float* __restrict__ spart) {
  const int j = blockIdx.x & 31;
  const int ch = blockIdx.x >> 5;
  const int tid = threadIdx.x;
  const int f0 = tid * 8;
  float acc[8] = {0, 0, 0, 0, 0, 0, 0, 0};
  const int i0 = ch * 32;
  const unsigned short* ubase = uhat + ((size_t)j * NI + i0) * (NB * NV) + f0;
#pragma unroll 4
  for (int ii = 0; ii < 32; ++ii) {
    const uint4 q = *(const uint4*)(ubase + (size_t)ii * (NB * NV));
    acc[0] += h2f((unsigned short)(q.x & 0xffff));
    acc[1] += h2f((unsigned short)(q.x >> 16));
    acc[2] += h2f((unsigned short)(q.y & 0xffff));
    acc[3] += h2f((unsigned short)(q.y >> 16));
    acc[4] += h2f((unsigned short)(q.z & 0xffff));
    acc[5] += h2f((unsigned short)(q.z >> 16));
    acc[6] += h2f((unsigned short)(q.w & 0xffff));
    acc[7] += h2f((unsigned short)(q.w >> 16));
  }
  const int b = f0 >> 5;
  const int v0 = f0 & 31;
  float* sp = spart + (size_t)ch * (NB * NJ * NV) + (size_t)b * (NJ * NV) + j * NV + v0;
  *(f32x4*)sp = (f32x4){acc[0], acc[1], acc[2], acc[3]};
  *(f32x4*)(sp + 4) = (f32x4){acc[4], acc[5], acc[6], acc[7]};
}

// ---------------------------------------------------------------------------
// fused routing pass (iterations 1,2) — 32 i per block:
//   agree = sum_{b,v} uhat[j][i][b][v] * vprev[b,j,v]   (block reduce)
//   bnew  = bprev + agree/64 ; w = exp(bnew)
//   stilde += w * uhat  ;  Zpart += w
// ---------------------------------------------------------------------------
__global__ __launch_bounds__(256) void k_route(
    const unsigned short* __restrict__ uhat, const float* __restrict__ vprev,
    const float* __restrict__ bin, float* __restrict__ bout,
    float* __restrict__ spart, float* __restrict__ Zpart) {
  const int j = blockIdx.x & 31;
  const int ch = blockIdx.x >> 5;
  const int tid = threadIdx.x;
  const int wave = tid >> 6;
  const int lane = tid & 63;
  const int f0 = tid * 8;
  const int b = f0 >> 5;
  const int v0 = f0 & 31;
  __shared__ float red[2][4];

  const float* vp = vprev + (size_t)b * (NJ * NV) + j * NV + v0;
  const f32x4 vva = *(const f32x4*)vp;
  const f32x4 vvb = *(const f32x4*)(vp + 4);

  float acc[8] = {0, 0, 0, 0, 0, 0, 0, 0};
  float zacc = 0.0f;
  const int i0 = ch * 32;
  const float* binj = bin ? (bin + (size_t)j * NI) : nullptr;
  float* boutj = bout + (size_t)j * NI;
  const unsigned short* ubase = uhat + ((size_t)j * NI + i0) * (NB * NV) + f0;

#pragma unroll 2
  for (int ii = 0; ii < 32; ++ii) {
    const int i = i0 + ii;
    const float bprev = binj ? binj[i] : 0.0f;
    const uint4 q = *(const uint4*)(ubase + (size_t)ii * (NB * NV));
    float h[8];
    h[0] = h2f((unsigned short)(q.x & 0xffff));
    h[1] = h2f((unsigned short)(q.x >> 16));
    h[2] = h2f((unsigned short)(q.y & 0xffff));
    h[3] = h2f((unsigned short)(q.y >> 16));
    h[4] = h2f((unsigned short)(q.z & 0xffff));
    h[5] = h2f((unsigned short)(q.z >> 16));
    h[6] = h2f((unsigned short)(q.w & 0xffff));
    h[7] = h2f((unsigned short)(q.w >> 16));
    float dp = h[0] * vva.x + h[1] * vva.y + h[2] * vva.z + h[3] * vva.w +
               h[4] * vvb.x + h[5] * vvb.y + h[6] * vvb.z + h[7] * vvb.w;
#pragma unroll
    for (int off = 32; off > 0; off >>= 1) dp += __shfl_xor(dp, off);
    const int par = ii & 1;
    if (lane == 0) red[par][wave] = dp;
    __syncthreads();
    const float agree = red[par][0] + red[par][1] + red[par][2] + red[par][3];
    const float bnew = bprev + agree * (1.0f / 64.0f);
    const float w = __expf(bnew);
    if (tid == 0) boutj[i] = bnew;
#pragma unroll
    for (int e = 0; e < 8; ++e) acc[e] = fmaf(w, h[e], acc[e]);
    zacc += w;
  }
  if (tid == 0) Zpart[ch * NJ + j] = zacc;
  float* sp = spart + (size_t)ch * (NB * NJ * NV) + (size_t)b * (NJ * NV) + j * NV + v0;
  *(f32x4*)sp = (f32x4){acc[0], acc[1], acc[2], acc[3]};
  *(f32x4*)(sp + 4) = (f32x4){acc[4], acc[5], acc[6], acc[7]};
}

// ---------------------------------------------------------------------------
// squash: s[b][j][v] = scale_j * sum_ch spart ; msq over j per (b,v);
// vout = msq/(1+msq) * s / sqrt(msq + 1e-9).  scale_j = 1/Z_j or scale0.
// ---------------------------------------------------------------------------
__global__ __launch_bounds__(1024) void k_squash(
    const float* __restrict__ spart, const float* __restrict__ Zpart,
    const float scale0, float* __restrict__ vout) {
  const int b = blockIdx.x;
  const int tid = threadIdx.x;
  const int j = tid >> 5;
  const int v = tid & 31;
  __shared__ float zs[NJ];
  if (Zpart != nullptr) {
    if (tid < NJ) {
      float z = 0.0f;
#pragma unroll 8
      for (int ch = 0; ch < NCH; ++ch) z += Zpart[ch * NJ + tid];
      zs[tid] = 1.0f / z;
    }
    __syncthreads();
  }
  const float scale = (Zpart != nullptr) ? zs[j] : scale0;
  float s = 0.0f;
#pragma unroll 8
  for (int ch = 0; ch < NCH; ++ch)
    s += spart[(size_t)ch * (NB * NJ * NV) + (size_t)b * (NJ * NV) + tid];
  s *= scale;
  __shared__ float sq[NJ][NV + 1];
  sq[j][v] = s * s;
  __syncthreads();
#pragma unroll
  for (int off = 16; off > 0; off >>= 1) {
    if (j < off) sq[j][v] += sq[j + off][v];
    __syncthreads();
  }
  const float msq = sq[0][v];
  const float f = msq / ((1.0f + msq) * sqrtf(msq + 1e-9f));
  vout[(size_t)b * (NJ * NV) + tid] = f * s;
}

// ---------------------------------------------------------------------------
extern "C" void kernel_launch(void* const* d_in, const int* in_sizes, int n_in,
                              void* d_out, int out_size, void* d_ws, size_t ws_size,
                              hipStream_t stream) {
  (void)in_sizes; (void)n_in; (void)out_size; (void)ws_size;
  const float* x = (const float*)d_in[0];
  const float* W = (const float*)d_in[1];
  float* out = (float*)d_out;

  char* ws = (char*)d_ws;
  const size_t UHAT_BYTES = (size_t)NI * NJ * NB * NV * 2;  // 268,435,456
  unsigned short* uhat = (unsigned short*)ws;                // [NJ][NI][NB][NV]
  float* bbuf = (float*)(ws + UHAT_BYTES);            // [NJ][NI]
  float* spart = bbuf + (size_t)NI * NJ;              // [NCH][NB][NJ][NV]
  float* vt = spart + (size_t)NCH * NB * NJ * NV;     // [NB][NJ][NV]
  float* Zpart = vt + (size_t)NB * NJ * NV;           // [NCH][NJ]

  k_uhat<<<dim3(NI), dim3(256), 0, stream>>>(x, W, uhat);

  // it0: c uniform -> s0 partials, squash with scale 1/2048
  k_pass0<<<dim3(NCH * NJ), dim3(256), 0, stream>>>(uhat, spart);
  k_squash<<<dim3(NB), dim3(1024), 0, stream>>>(spart, nullptr, 1.0f / NI, vt);

  // it1: agree0 + unnormalized s1 in one pass (b starts at 0)
  k_route<<<dim3(NCH * NJ), dim3(256), 0, stream>>>(uhat, vt, nullptr, bbuf, spart, Zpart);
  k_squash<<<dim3(NB), dim3(1024), 0, stream>>>(spart, Zpart, 0.0f, vt);

  // it2: agree1 + unnormalized s2 in one pass
  k_route<<<dim3(NCH * NJ), dim3(256), 0, stream>>>(uhat, vt, bbuf, bbuf, spart, Zpart);
  k_squash<<<dim3(NB), dim3(1024), 0, stream>>>(spart, Zpart, 0.0f, out);
}